// Round 7
// baseline (509.669 us; speedup 1.0000x reference)
//
#include <hip/hip_runtime.h>
#include <stdint.h>

#define B_    4
#define N_    2048
#define D_    4096
#define E_    64
#define TOKENS (B_ * N_)        // 8192
#define KS    8                 // in-block split-K (8 waves per block)
#define KCH   (D_ / KS)         // 512 k's per wave
#define TPW   16                // tokens per block (all waves share them)

typedef float vfloat4 __attribute__((ext_vector_type(4)));

// ---------------------------------------------------------------------------
// K1 (fused): GEMV-style router gemm + softmax/argmax/losses + d_out zero.
// Block = 512 thr = 8 waves; block owns 16 tokens; wave wv does k-chunk wv.
// lane = expert. W[k,0:64] = one coalesced 256B vector load (L2-resident);
// A[t,k] is wave-uniform -> scalar (SGPR) broadcast into v_fmac. NO LDS in
// the main loop. LDS only for the 8-way partial reduction + softmax.
// Each block then streams its zero slice of d_out (NT stores).
// ---------------------------------------------------------------------------
__global__ __launch_bounds__(512) void k_fused(const float* __restrict__ A,
                                               const float* __restrict__ W,
                                               int* __restrict__ idx,
                                               float* __restrict__ gate,
                                               float* __restrict__ probsum,
                                               float* __restrict__ out,
                                               float* __restrict__ out_z,
                                               int qpt) {   // float4 zero-stores per thread
    __shared__ float part[KS][TPW][E_];   // 32 KB

    const int tid  = threadIdx.x;
    const int lane = tid & 63;
    const int wv   = __builtin_amdgcn_readfirstlane(tid >> 6);  // 0..7, uniform
    const int tok0 = blockIdx.x * TPW;

    const float* __restrict__ Ab = A + (size_t)tok0 * D_ + (size_t)wv * KCH;
    const float* __restrict__ Wb = W + (size_t)wv * KCH * E_ + lane;

    float acc[TPW];
    #pragma unroll
    for (int t = 0; t < TPW; ++t) acc[t] = 0.f;

    #pragma unroll 1
    for (int k = 0; k < KCH; k += 8) {
        float w[8];
        #pragma unroll
        for (int j = 0; j < 8; ++j)
            w[j] = Wb[(size_t)(k + j) * E_];          // vector, coalesced, L2
        #pragma unroll
        for (int t = 0; t < TPW; ++t) {
            const float* __restrict__ ar = Ab + (size_t)t * D_ + k;  // uniform
            float a = acc[t];
            a = fmaf(ar[0], w[0], a);
            a = fmaf(ar[1], w[1], a);
            a = fmaf(ar[2], w[2], a);
            a = fmaf(ar[3], w[3], a);
            a = fmaf(ar[4], w[4], a);
            a = fmaf(ar[5], w[5], a);
            a = fmaf(ar[6], w[6], a);
            a = fmaf(ar[7], w[7], a);
            acc[t] = a;
        }
    }

    // ---- zero-fill slice of d_out (issued early; drains under later phases)
    {
        vfloat4* zb = reinterpret_cast<vfloat4*>(out)
                    + (size_t)blockIdx.x * (size_t)qpt * 512 + tid;
        const vfloat4 z4 = {0.f, 0.f, 0.f, 0.f};
        #pragma unroll 1
        for (int s = 0; s < qpt; ++s)
            __builtin_nontemporal_store(z4, zb + (size_t)s * 512);
    }

    // ---- stage partials
    #pragma unroll
    for (int t = 0; t < TPW; ++t)
        part[wv][t][lane] = acc[t];
    __syncthreads();

    // ---- wave wv reduces + softmaxes tokens 2wv, 2wv+1
    float prob2 = 0.f, zsq2 = 0.f;
    #pragma unroll
    for (int j = 0; j < 2; ++j) {
        const int t = wv * 2 + j;
        float l = 0.f;
        #pragma unroll
        for (int p = 0; p < KS; ++p) l += part[p][t][lane];

        float m = l; int mi = lane;                   // argmax, first-index ties
        #pragma unroll
        for (int off = 32; off > 0; off >>= 1) {
            const float om = __shfl_down(m, off);
            const int   oi = __shfl_down(mi, off);
            if (om > m || (om == m && oi < mi)) { m = om; mi = oi; }
        }
        m  = __shfl(m, 0);
        mi = __shfl(mi, 0);

        const float pe = __expf(l - m);
        float s = pe;
        #pragma unroll
        for (int off = 32; off > 0; off >>= 1) s += __shfl_down(s, off);
        s = __shfl(s, 0);

        prob2 += pe / s;
        const float lse = m + logf(s);
        zsq2 += lse * lse;
        if (lane == 0) {
            idx[tok0 + t]  = mi;
            gate[tok0 + t] = 1.0f / s;                // max prob
        }
    }
    __syncthreads();                                  // all part reads done

    part[wv][0][lane] = prob2;                        // per-wave prob sums
    if (lane == 0) part[wv][1][0] = zsq2;
    __syncthreads();

    if (wv == 0) {
        float ps = 0.f;
        #pragma unroll
        for (int p = 0; p < KS; ++p) ps += part[p][0][lane];
        const int b = tok0 / N_;                      // 16 | 2048: no crossing
        atomicAdd(&probsum[b * E_ + lane], ps);
        if (lane == 0) {
            float z = 0.f;
            #pragma unroll
            for (int p = 0; p < KS; ++p) z += part[p][1][0];
            atomicAdd(out_z, z * (1.0f / (float)TOKENS));
        }
    }
}

// ---------------------------------------------------------------------------
// K2: ordered position-in-expert via wave ballot (matches reference cumsum),
// scatter into dispatch/combine + aux-loss fused. One wave per (b,e).
// ---------------------------------------------------------------------------
__global__ __launch_bounds__(64) void k_posloss(const int* __restrict__ idx,
                                                const float* __restrict__ gate,
                                                const float* __restrict__ probsum,
                                                float* __restrict__ out,
                                                float* __restrict__ out_aux,
                                                int C, size_t half) {
    const int b = blockIdx.x >> 6;
    const int e = blockIdx.x & 63;
    const int lane = threadIdx.x;
    const int*   ib = idx  + b * N_;
    const float* gb = gate + b * N_;
    float* ob = out + (size_t)b * N_ * E_ * C;   // dispatch base for batch b

    int running = 0;
    for (int step = 0; step < N_ / 64; ++step) {
        const int t = step * 64 + lane;
        const bool match = (ib[t] == e);
        const unsigned long long mask = __ballot(match);
        if (match) {
            const int p = running + __popcll(mask & ((1ull << lane) - 1ull));
            if (p < C) {
                const size_t off = (size_t)t * E_ * C + (size_t)e * C + p;
                ob[off] = 1.0f;            // dispatch
                ob[half + off] = gb[t];    // combine
            }
        }
        running += __popcll(mask);
    }
    if (lane == 0)   // aux = sum(count * probsum) * E^2/(B*E*N*N) = sum/262144
        atomicAdd(out_aux,
                  (float)running * probsum[b * E_ + e] * (1.0f / 262144.0f));
}

// ---------------------------------------------------------------------------
extern "C" void kernel_launch(void* const* d_in, const int* in_sizes, int n_in,
                              void* d_out, int out_size, void* d_ws, size_t ws_size,
                              hipStream_t stream) {
    const float* A = (const float*)d_in[0];
    const float* W = (const float*)d_in[1];
    float* out = (float*)d_out;

    const size_t half = ((size_t)out_size - 2) / 2;          // TOKENS*E*C
    const int C = (int)(half / ((size_t)TOKENS * E_));       // 40
    const int nblocks = TOKENS / TPW;                        // 512
    // float4 zero-stores per thread: (2*half/4) / (nblocks*512)
    const int qpt = (int)((half / 2) / ((size_t)nblocks * 512));

    float* gate    = (float*)d_ws;
    int*   idx     = (int*)(gate + TOKENS);
    float* probsum = (float*)(gate + 2 * TOKENS);

    float* out_aux = out + 2 * half;
    float* out_z   = out + 2 * half + 1;

    hipMemsetAsync(probsum, 0, B_ * E_ * sizeof(float), stream);
    hipMemsetAsync(out_aux, 0, 2 * sizeof(float), stream);

    k_fused<<<nblocks, 512, 0, stream>>>(A, W, idx, gate, probsum, out,
                                         out_z, qpt);
    k_posloss<<<B_ * E_, 64, 0, stream>>>(idx, gate, probsum, out, out_aux,
                                          C, half);
}